// Round 7
// baseline (503.991 us; speedup 1.0000x reference)
//
#include <hip/hip_runtime.h>

#define NNODES 50000

typedef _Float16 half8 __attribute__((ext_vector_type(8)));
typedef float f32x4 __attribute__((ext_vector_type(4)));

__device__ __forceinline__ float sigm(float x)   { return 1.f / (1.f + __expf(-x)); }
__device__ __forceinline__ float tanh_f(float x) { float e = __expf(2.f * x); return 1.f - 2.f / (e + 1.f); }

// ---------------------------------------------------------------------------
// WpT[512 cols][288 k] fp16. k<128: W_child[2g][k][d]; k<256: W_child[2g+1][k-128][d]
// (col c -> gate g=c>>7, d=c&127). k in 256..287 filled by k_prep_table (op tab).
__global__ __launch_bounds__(256) void k_prep_wpT(const float* __restrict__ Wc,
                                                  _Float16* __restrict__ WpT) {
    int i = blockIdx.x * 256 + threadIdx.x;      // 0..131071
    int c = i >> 8, k = i & 255;
    int g = c >> 7, d = c & 127;
    float v = (k < 128) ? Wc[(2 * g) * 16384 + k * 128 + d]
                        : Wc[(2 * g + 1) * 16384 + (k - 128) * 128 + d];
    WpT[c * 288 + k] = (_Float16)v;
}

// tab rows of WpT: WpT[c*288 + 256 + t] = char_emb[t]@W_x[gx] + b_x[gx] + b_child[2g] + b_child[2g+1]
__global__ __launch_bounds__(256) void k_prep_table(const float* __restrict__ ce,
                                                    const float* __restrict__ Wx,
                                                    const float* __restrict__ bx,
                                                    const float* __restrict__ bc,
                                                    _Float16* __restrict__ WpT) {
    int i = blockIdx.x * 256 + threadIdx.x;      // 0..16383
    int tt = i >> 9, c = i & 511;
    int g = c >> 7, d = c & 127;
    int gx = (g == 0) ? 0 : ((g == 3) ? 2 : 1);
    float acc = bx[gx * 128 + d] + bc[(2 * g) * 128 + d] + bc[(2 * g + 1) * 128 + d];
    const float* x = ce + tt * 128;
    const float* w = Wx + gx * 16384 + d;
    for (int l = 0; l < 128; ++l) acc += x[l] * w[l * 128];
    WpT[c * 288 + 256 + tt] = (_Float16)acc;
}

// WlT[256 cols][128 k] fp16
__global__ __launch_bounds__(256) void k_prep_wlT(const float* __restrict__ Wl,
                                                  _Float16* __restrict__ WlT) {
    int i = blockIdx.x * 256 + threadIdx.x;      // 0..32767
    int c = i >> 7, k = i & 127;
    WlT[i] = (_Float16)Wl[(c >> 7) * 16384 + k * 128 + (c & 127)];
}

// ---------------------------------------------------------------------------
// Leaf tables: [50000 x 128] fp32 -> c_tab fp16, h_tab fp16 via f16 MFMA
__global__ __launch_bounds__(256) void k_prep_nodes(const float* __restrict__ ne,
                                                    const _Float16* __restrict__ WlT,
                                                    const float* __restrict__ bl,
                                                    _Float16* __restrict__ c_tab,
                                                    _Float16* __restrict__ h_tab) {
    const int t = threadIdx.x;
    const int w = t >> 6, l = t & 63;
    const int lr = l & 15, lq = l >> 4;
    const int nb = blockIdx.x * 32;

    int arow[2];
#pragma unroll
    for (int rt = 0; rt < 2; ++rt) {
        int r = nb + rt * 16 + lr;
        arow[rt] = (r < NNODES) ? r : (NNODES - 1);
    }

    f32x4 acc[2][2][2];
#pragma unroll
    for (int rt = 0; rt < 2; ++rt)
#pragma unroll
        for (int g = 0; g < 2; ++g)
#pragma unroll
            for (int ti = 0; ti < 2; ++ti) acc[rt][g][ti] = (f32x4)0.f;

#pragma unroll
    for (int kk = 0; kk < 4; ++kk) {
        half8 af[2];
#pragma unroll
        for (int rt = 0; rt < 2; ++rt) {
            const float* src = ne + (size_t)arow[rt] * 128 + kk * 32 + lq * 8;
            float4 f0 = *(const float4*)src;
            float4 f1 = *(const float4*)(src + 4);
            half8 v;
            v[0] = (_Float16)f0.x; v[1] = (_Float16)f0.y; v[2] = (_Float16)f0.z; v[3] = (_Float16)f0.w;
            v[4] = (_Float16)f1.x; v[5] = (_Float16)f1.y; v[6] = (_Float16)f1.z; v[7] = (_Float16)f1.w;
            af[rt] = v;
        }
#pragma unroll
        for (int g = 0; g < 2; ++g)
#pragma unroll
            for (int ti = 0; ti < 2; ++ti) {
                int col = g * 128 + w * 32 + ti * 16 + lr;
                half8 bb = *(const half8*)(WlT + col * 128 + kk * 32 + lq * 8);
#pragma unroll
                for (int rt = 0; rt < 2; ++rt)
                    acc[rt][g][ti] = __builtin_amdgcn_mfma_f32_16x16x32_f16(af[rt], bb, acc[rt][g][ti], 0, 0, 0);
            }
    }

#pragma unroll
    for (int rt = 0; rt < 2; ++rt)
#pragma unroll
        for (int j = 0; j < 4; ++j) {
            int r = nb + rt * 16 + lq * 4 + j;
            if (r < NNODES) {
#pragma unroll
                for (int ti = 0; ti < 2; ++ti) {
                    int d = w * 32 + ti * 16 + lr;
                    float cc = acc[rt][0][ti][j] + bl[d];
                    float hp = acc[rt][1][ti][j] + bl[128 + d];
                    c_tab[(size_t)r * 128 + d] = (_Float16)cc;
                    h_tab[(size_t)r * 128 + d] = (_Float16)(sigm(hp) * tanh_f(cc));
                }
            }
        }
}

// ---------------------------------------------------------------------------
// k_lo: levels 0-2 fused. 1024 blocks x 256 threads (4 waves x 32-col slices).
// Unified-register budget (r5/r6 lesson): acc 64 AGPR + ~80 arch VGPR ~ 150
// unified -> 3 waves/SIMD at cap 170 (launch_bounds(256,3)). No A prefetch
// (TLP hides L2 latency), no c-stage LDS (lc/rc via early register gathers).
// LDS 34 KB.
__global__ __launch_bounds__(256, 3) void k_lo(const _Float16* __restrict__ c_tab,
                                               const _Float16* __restrict__ h_tab,
                                               const int* __restrict__ leaf_idx,
                                               const int* __restrict__ op_idx,
                                               const _Float16* __restrict__ WpT,
                                               float* __restrict__ g2c,
                                               _Float16* __restrict__ g2h) {
    __shared__ int s_leaf[128];
    __shared__ int s_op[112];
    __shared__ _Float16 s_h0[64 * 128];     // swizzled; rows 0-31 reused for L1 out
    __shared__ _Float16 s_c0[64 * 132];

    const int t = threadIdx.x;
    const int w = t >> 6, l = t & 63, lr = l & 15, lq = l >> 4;
    const int ks = blockIdx.x >> 4, seg = blockIdx.x & 15;

    if (t < 128) s_leaf[t] = leaf_idx[ks * 2048 + seg * 128 + t];
    else if (t < 192) s_op[t - 128] = op_idx[ks * 2047 + seg * 64 + (t - 128)];
    else if (t < 224) s_op[64 + t - 192] = op_idx[ks * 2047 + 1024 + seg * 32 + (t - 192)];
    else if (t < 240) s_op[96 + t - 224] = op_idx[ks * 2047 + 1536 + seg * 16 + (t - 224)];
    __syncthreads();

    // ---- level 0: two 32-pair halves, no barrier between them ----
#pragma unroll 1
    for (int h = 0; h < 2; ++h) {
        // early lc/rc gathers for this half's epilogue (32 fp16 regs)
        _Float16 lcv[2][2][4], rcv[2][2][4];
#pragma unroll
        for (int rt = 0; rt < 2; ++rt)
#pragma unroll
            for (int j = 0; j < 4; ++j) {
                int p = h * 32 + rt * 16 + lq * 4 + j;
                int rl = s_leaf[2 * p], rr = s_leaf[2 * p + 1];
#pragma unroll
                for (int ti = 0; ti < 2; ++ti) {
                    int d = w * 32 + ti * 16 + lr;
                    lcv[rt][ti][j] = c_tab[(size_t)rl * 128 + d];
                    rcv[rt][ti][j] = c_tab[(size_t)rr * 128 + d];
                }
            }

        int grow[2][2], opv[2];
#pragma unroll
        for (int rt = 0; rt < 2; ++rt) {
            int pg = h * 32 + rt * 16 + lr;
            grow[rt][0] = s_leaf[2 * pg];
            grow[rt][1] = s_leaf[2 * pg + 1];
            opv[rt] = s_op[pg];
        }

        f32x4 acc[2][4][2];
#pragma unroll
        for (int rt = 0; rt < 2; ++rt)
#pragma unroll
            for (int g = 0; g < 4; ++g)
#pragma unroll
                for (int ti = 0; ti < 2; ++ti) acc[rt][g][ti] = (f32x4)0.f;

#pragma unroll
        for (int kk = 0; kk < 9; ++kk) {
            half8 a[2];
            if (kk < 8) {
                int side = kk >> 2, ko = (kk & 3) * 32 + lq * 8;
#pragma unroll
                for (int rt = 0; rt < 2; ++rt)
                    a[rt] = *(const half8*)(h_tab + (size_t)grow[rt][side] * 128 + ko);
            } else {
#pragma unroll
                for (int rt = 0; rt < 2; ++rt)
#pragma unroll
                    for (int i = 0; i < 8; ++i)
                        a[rt][i] = (_Float16)((lq * 8 + i) == opv[rt] ? 1.f : 0.f);
            }
#pragma unroll
            for (int g = 0; g < 4; ++g)
#pragma unroll
                for (int ti = 0; ti < 2; ++ti) {
                    half8 bb = *(const half8*)(WpT + (g * 128 + w * 32 + ti * 16 + lr) * 288 + kk * 32 + lq * 8);
#pragma unroll
                    for (int rt = 0; rt < 2; ++rt)
                        acc[rt][g][ti] = __builtin_amdgcn_mfma_f32_16x16x32_f16(a[rt], bb, acc[rt][g][ti], 0, 0, 0);
                }
        }

        // epilogue (lc/rc from registers; own-row LDS writes, no barrier needed)
#pragma unroll
        for (int rt = 0; rt < 2; ++rt)
#pragma unroll
            for (int j = 0; j < 4; ++j) {
                int p = h * 32 + rt * 16 + lq * 4 + j;
#pragma unroll
                for (int ti = 0; ti < 2; ++ti) {
                    int d = w * 32 + ti * 16 + lr;
                    float vi = acc[rt][0][ti][j], vl = acc[rt][1][ti][j];
                    float vr = acc[rt][2][ti][j], vu = acc[rt][3][ti][j];
                    float cc = sigm(vi) * tanh_f(vu) + sigm(vl) * (float)lcv[rt][ti][j]
                             + sigm(vr) * (float)rcv[rt][ti][j];
                    s_c0[p * 132 + d] = (_Float16)cc;
                    s_h0[p * 128 + (d ^ ((p & 15) << 3))] = (_Float16)tanh_f(cc);
                }
            }
    }
    __syncthreads();   // h0/c0 (64 rows) complete

    // ---- level 1: 32 pairs; outputs buffered in regs, then rows 0..31 ----
    int opv1[2];
    opv1[0] = s_op[64 + lr]; opv1[1] = s_op[80 + lr];
    f32x4 acc1[2][4][2];
#pragma unroll
    for (int rt = 0; rt < 2; ++rt)
#pragma unroll
        for (int g = 0; g < 4; ++g)
#pragma unroll
            for (int ti = 0; ti < 2; ++ti) acc1[rt][g][ti] = (f32x4)0.f;

#pragma unroll
    for (int kk = 0; kk < 9; ++kk) {
        half8 a[2];
        if (kk < 8) {
            int side = kk >> 2, ko = (kk & 3) * 32 + lq * 8;
#pragma unroll
            for (int rt = 0; rt < 2; ++rt) {
                int child = 2 * (rt * 16 + lr) + side;
                a[rt] = *(const half8*)(s_h0 + child * 128 + (ko ^ ((child & 15) << 3)));
            }
        } else {
#pragma unroll
            for (int rt = 0; rt < 2; ++rt)
#pragma unroll
                for (int i = 0; i < 8; ++i)
                    a[rt][i] = (_Float16)((lq * 8 + i) == opv1[rt] ? 1.f : 0.f);
        }
#pragma unroll
        for (int g = 0; g < 4; ++g)
#pragma unroll
            for (int ti = 0; ti < 2; ++ti) {
                half8 bb = *(const half8*)(WpT + (g * 128 + w * 32 + ti * 16 + lr) * 288 + kk * 32 + lq * 8);
#pragma unroll
                for (int rt = 0; rt < 2; ++rt)
                    acc1[rt][g][ti] = __builtin_amdgcn_mfma_f32_16x16x32_f16(a[rt], bb, acc1[rt][g][ti], 0, 0, 0);
            }
    }

    _Float16 c1v[2][2][4], h1v[2][2][4];
#pragma unroll
    for (int rt = 0; rt < 2; ++rt)
#pragma unroll
        for (int j = 0; j < 4; ++j) {
            int p = rt * 16 + lq * 4 + j;
#pragma unroll
            for (int ti = 0; ti < 2; ++ti) {
                int d = w * 32 + ti * 16 + lr;
                float vi = acc1[rt][0][ti][j], vl = acc1[rt][1][ti][j];
                float vr = acc1[rt][2][ti][j], vu = acc1[rt][3][ti][j];
                float lc = (float)s_c0[(2 * p) * 132 + d];
                float rc = (float)s_c0[(2 * p + 1) * 132 + d];
                float cc = sigm(vi) * tanh_f(vu) + sigm(vl) * lc + sigm(vr) * rc;
                c1v[rt][ti][j] = (_Float16)cc;
                h1v[rt][ti][j] = (_Float16)tanh_f(cc);
            }
        }
    __syncthreads();   // all reads of h0/c0 done
#pragma unroll
    for (int rt = 0; rt < 2; ++rt)
#pragma unroll
        for (int j = 0; j < 4; ++j) {
            int p = rt * 16 + lq * 4 + j;
#pragma unroll
            for (int ti = 0; ti < 2; ++ti) {
                int d = w * 32 + ti * 16 + lr;
                s_c0[p * 132 + d] = c1v[rt][ti][j];
                s_h0[p * 128 + (d ^ ((p & 15) << 3))] = h1v[rt][ti][j];
            }
        }
    __syncthreads();

    // ---- level 2: 16 pairs -> global ----
    int opv2 = s_op[96 + lr];
    f32x4 acc2[4][2];
#pragma unroll
    for (int g = 0; g < 4; ++g)
#pragma unroll
        for (int ti = 0; ti < 2; ++ti) acc2[g][ti] = (f32x4)0.f;

#pragma unroll
    for (int kk = 0; kk < 9; ++kk) {
        half8 a;
        if (kk < 8) {
            int side = kk >> 2, ko = (kk & 3) * 32 + lq * 8;
            int child = 2 * lr + side;
            a = *(const half8*)(s_h0 + child * 128 + (ko ^ ((child & 15) << 3)));
        } else {
#pragma unroll
            for (int i = 0; i < 8; ++i)
                a[i] = (_Float16)((lq * 8 + i) == opv2 ? 1.f : 0.f);
        }
#pragma unroll
        for (int g = 0; g < 4; ++g)
#pragma unroll
            for (int ti = 0; ti < 2; ++ti) {
                half8 bb = *(const half8*)(WpT + (g * 128 + w * 32 + ti * 16 + lr) * 288 + kk * 32 + lq * 8);
                acc2[g][ti] = __builtin_amdgcn_mfma_f32_16x16x32_f16(a, bb, acc2[g][ti], 0, 0, 0);
            }
    }

#pragma unroll
    for (int j = 0; j < 4; ++j) {
        int p = lq * 4 + j;
#pragma unroll
        for (int ti = 0; ti < 2; ++ti) {
            int d = w * 32 + ti * 16 + lr;
            float vi = acc2[0][ti][j], vl = acc2[1][ti][j];
            float vr = acc2[2][ti][j], vu = acc2[3][ti][j];
            float lc = (float)s_c0[(2 * p) * 132 + d];
            float rc = (float)s_c0[(2 * p + 1) * 132 + d];
            float cc = sigm(vi) * tanh_f(vu) + sigm(vl) * lc + sigm(vr) * rc;
            size_t orow = (size_t)blockIdx.x * 16 + p;
            g2c[orow * 128 + d] = cc;
            g2h[orow * 128 + d] = (_Float16)tanh_f(cc);
        }
    }
}

// ---------------------------------------------------------------------------
// Generic mid level: 32 pairs/block, 512 threads, no LDS. Children are
// contiguous rows 2p,2p+1 of the previous level's dense output.
__global__ __launch_bounds__(512, 4) void k_level(const float* __restrict__ c_src,
                                                  const _Float16* __restrict__ h_src,
                                                  float* __restrict__ c_dst,
                                                  _Float16* __restrict__ h_dst,
                                                  const _Float16* __restrict__ WpT,
                                                  const int* __restrict__ op_idx,
                                                  int op_start, int mshift) {
    const int t = threadIdx.x;
    const int w = t >> 6, l = t & 63, lr = l & 15, lq = l >> 4;
    const int pbase = blockIdx.x * 32;

    int opv[2];
#pragma unroll
    for (int rt = 0; rt < 2; ++rt) {
        int pg = pbase + rt * 16 + lr;
        int ksx = pg >> mshift, j = pg & ((1 << mshift) - 1);
        opv[rt] = op_idx[ksx * 2047 + op_start + j];
    }

    f32x4 acc[2][4];
#pragma unroll
    for (int rt = 0; rt < 2; ++rt)
#pragma unroll
        for (int g = 0; g < 4; ++g) acc[rt][g] = (f32x4)0.f;

#pragma unroll
    for (int kk = 0; kk < 9; ++kk) {
        half8 a[2];
        if (kk < 8) {
            int side = kk >> 2, ko = (kk & 3) * 32 + lq * 8;
#pragma unroll
            for (int rt = 0; rt < 2; ++rt) {
                int row = 2 * (pbase + rt * 16 + lr) + side;
                a[rt] = *(const half8*)(h_src + (size_t)row * 128 + ko);
            }
        } else {
#pragma unroll
            for (int rt = 0; rt < 2; ++rt)
#pragma unroll
                for (int i = 0; i < 8; ++i)
                    a[rt][i] = (_Float16)((lq * 8 + i) == opv[rt] ? 1.f : 0.f);
        }
#pragma unroll
        for (int g = 0; g < 4; ++g) {
            half8 bb = *(const half8*)(WpT + (g * 128 + w * 16 + lr) * 288 + kk * 32 + lq * 8);
#pragma unroll
            for (int rt = 0; rt < 2; ++rt)
                acc[rt][g] = __builtin_amdgcn_mfma_f32_16x16x32_f16(a[rt], bb, acc[rt][g], 0, 0, 0);
        }
    }

    const int d = w * 16 + lr;
#pragma unroll
    for (int rt = 0; rt < 2; ++rt)
#pragma unroll
        for (int j = 0; j < 4; ++j) {
            int p = pbase + rt * 16 + lq * 4 + j;
            float vi = acc[rt][0][j], vl = acc[rt][1][j], vr = acc[rt][2][j], vu = acc[rt][3][j];
            float lc = c_src[(size_t)(2 * p) * 128 + d];
            float rc = c_src[(size_t)(2 * p + 1) * 128 + d];
            float cc = sigm(vi) * tanh_f(vu) + sigm(vl) * lc + sigm(vr) * rc;
            c_dst[(size_t)p * 128 + d] = cc;
            h_dst[(size_t)p * 128 + d] = (_Float16)tanh_f(cc);
        }
}

// ---------------------------------------------------------------------------
// k_deep: levels 6-10 + AND projection. One block per tree, WpT held in regs.
template <bool GSRC>
__device__ __forceinline__ void deep_pass(int np, int opoff,
                                          const _Float16* hS, const _Float16* cS,
                                          const _Float16* __restrict__ gh,
                                          const float* __restrict__ gc, int rowbase,
                                          _Float16* hD, _Float16* cD,
                                          const half8 (&B)[9][4],
                                          const int* s_op, int w, int lq, int lr) {
    f32x4 acc[4];
#pragma unroll
    for (int g = 0; g < 4; ++g) acc[g] = (f32x4)0.f;
    int pidx = lr < np ? lr : np - 1;
    int op = s_op[opoff + pidx];
#pragma unroll
    for (int kk = 0; kk < 9; ++kk) {
        half8 a;
        if (kk < 8) {
            int side = kk >> 2, ko = (kk & 3) * 32 + lq * 8;
            int child = 2 * pidx + side;
            if constexpr (GSRC)
                a = *(const half8*)(gh + (size_t)(rowbase + child) * 128 + ko);
            else
                a = *(const half8*)(hS + child * 128 + (ko ^ ((child & 15) << 3)));
        } else {
#pragma unroll
            for (int i = 0; i < 8; ++i)
                a[i] = (_Float16)((lq * 8 + i) == op ? 1.f : 0.f);
        }
#pragma unroll
        for (int g = 0; g < 4; ++g)
            acc[g] = __builtin_amdgcn_mfma_f32_16x16x32_f16(a, B[kk][g], acc[g], 0, 0, 0);
    }
    const int d = w * 16 + lr;
#pragma unroll
    for (int j = 0; j < 4; ++j) {
        int p = lq * 4 + j;
        if (p < np) {
            float vi = acc[0][j], vl = acc[1][j], vr = acc[2][j], vu = acc[3][j];
            float lc, rc;
            if constexpr (GSRC) {
                lc = gc[(size_t)(rowbase + 2 * p) * 128 + d];
                rc = gc[(size_t)(rowbase + 2 * p + 1) * 128 + d];
            } else {
                lc = (float)cS[(2 * p) * 132 + d];
                rc = (float)cS[(2 * p + 1) * 132 + d];
            }
            float cc = sigm(vi) * tanh_f(vu) + sigm(vl) * lc + sigm(vr) * rc;
            cD[p * 132 + d] = (_Float16)cc;
            hD[p * 128 + (d ^ ((p & 15) << 3))] = (_Float16)tanh_f(cc);
        }
    }
}

__global__ __launch_bounds__(512, 2) void k_deep(const float* __restrict__ g5c,
                                                 const _Float16* __restrict__ g5h,
                                                 const int* __restrict__ op_idx,
                                                 const _Float16* __restrict__ WpT,
                                                 const float* __restrict__ Wa,
                                                 const float* __restrict__ ba,
                                                 float* __restrict__ c2,
                                                 float* __restrict__ h2) {
    __shared__ int s_op[32];
    __shared__ _Float16 hA[16 * 128], cA[16 * 132];
    __shared__ _Float16 hB[8 * 128],  cB[8 * 132];
    const int t = threadIdx.x, w = t >> 6, l = t & 63, lr = l & 15, lq = l >> 4;
    const int tree = blockIdx.x;

    if (t < 31) s_op[t] = op_idx[tree * 2047 + 2016 + t];   // L6:0..15 L7:16..23 L8:24..27 L9:28..29 L10:30
    __syncthreads();

    half8 B[9][4];
#pragma unroll
    for (int kk = 0; kk < 9; ++kk)
#pragma unroll
        for (int g = 0; g < 4; ++g)
            B[kk][g] = *(const half8*)(WpT + (g * 128 + w * 16 + lr) * 288 + kk * 32 + lq * 8);

    deep_pass<true >(16,  0, nullptr, nullptr, g5h, g5c, tree * 32, hA, cA, B, s_op, w, lq, lr);
    __syncthreads();
    deep_pass<false>( 8, 16, hA, cA, nullptr, nullptr, 0, hB, cB, B, s_op, w, lq, lr);
    __syncthreads();
    deep_pass<false>( 4, 24, hB, cB, nullptr, nullptr, 0, hA, cA, B, s_op, w, lq, lr);
    __syncthreads();
    deep_pass<false>( 2, 28, hA, cA, nullptr, nullptr, 0, hB, cB, B, s_op, w, lq, lr);
    __syncthreads();
    deep_pass<false>( 1, 30, hB, cB, nullptr, nullptr, 0, hA, cA, B, s_op, w, lq, lr);
    __syncthreads();

    // AND projection (root = row 0 of A; p=0 swizzle is identity)
    if (t < 256) {
        int dd = t & 127;
        if (t < 128) {
            float a = ba[dd];
            for (int ll = 0; ll < 128; ++ll) a += (float)cA[ll] * Wa[ll * 128 + dd];
            c2[tree * 128 + dd] = a;
        } else {
            float a = ba[128 + dd];
            for (int ll = 0; ll < 128; ++ll) a += (float)hA[ll] * Wa[16384 + ll * 128 + dd];
            h2[tree * 128 + dd] = a;
        }
    }
}

// ---------------------------------------------------------------------------
__global__ __launch_bounds__(128) void k_final(const float* __restrict__ c2,
                                               const float* __restrict__ h2,
                                               const float* __restrict__ init_e,
                                               const float* __restrict__ Wo,
                                               const float* __restrict__ bo,
                                               float* __restrict__ out) {
    __shared__ float s[384];
    const int d = threadIdx.x;
    float cm = c2[d], hm = h2[d];
    for (int k = 1; k < 64; ++k) {
        cm = fminf(cm, c2[k * 128 + d]);
        hm = fminf(hm, h2[k * 128 + d]);
    }
    s[d] = init_e[d];
    s[128 + d] = cm;
    s[256 + d] = hm;
    __syncthreads();
    float a = bo[d];
    for (int l = 0; l < 384; ++l) a += s[l] * Wo[l * 128 + d];
    out[d] = tanhf(a);
}

// ---------------------------------------------------------------------------
extern "C" void kernel_launch(void* const* d_in, const int* in_sizes, int n_in,
                              void* d_out, int out_size, void* d_ws, size_t ws_size,
                              hipStream_t stream) {
    const float* node_emb = (const float*)d_in[0];
    const float* init_emb = (const float*)d_in[1];
    const float* char_emb = (const float*)d_in[2];
    const float* W_child  = (const float*)d_in[3];
    const float* b_child  = (const float*)d_in[4];
    const float* W_x      = (const float*)d_in[5];
    const float* b_x      = (const float*)d_in[6];
    const float* W_leaf   = (const float*)d_in[7];
    const float* b_leaf   = (const float*)d_in[8];
    const float* W_and    = (const float*)d_in[9];
    const float* b_and    = (const float*)d_in[10];
    const float* W_oend   = (const float*)d_in[11];
    const float* b_oend   = (const float*)d_in[12];
    const int* leaf_idx   = (const int*)d_in[13];
    const int* op_idx     = (const int*)d_in[14];
    float* out = (float*)d_out;
    (void)in_sizes; (void)n_in; (void)out_size; (void)ws_size;

    char* p = (char*)d_ws;
    auto carve = [&](size_t bytes) { char* r = p; p += (bytes + 255) & ~255ull; return r; };
    _Float16* WpT   = (_Float16*)carve((size_t)512 * 288 * 2);
    _Float16* WlT   = (_Float16*)carve((size_t)256 * 128 * 2);
    _Float16* c_tab = (_Float16*)carve((size_t)NNODES * 128 * 2);
    _Float16* h_tab = (_Float16*)carve((size_t)NNODES * 128 * 2);
    float*    g2c   = (float*)carve((size_t)16384 * 128 * 4);
    _Float16* g2h   = (_Float16*)carve((size_t)16384 * 128 * 2);
    float*    g3c   = (float*)carve((size_t)8192 * 128 * 4);
    _Float16* g3h   = (_Float16*)carve((size_t)8192 * 128 * 2);
    float*    g4c   = (float*)carve((size_t)4096 * 128 * 4);
    _Float16* g4h   = (_Float16*)carve((size_t)4096 * 128 * 2);
    float*    g5c   = (float*)carve((size_t)2048 * 128 * 4);
    _Float16* g5h   = (_Float16*)carve((size_t)2048 * 128 * 2);
    float*    c2    = (float*)carve(64 * 128 * 4);
    float*    h2    = (float*)carve(64 * 128 * 4);

    k_prep_wpT  <<<512, 256, 0, stream>>>(W_child, WpT);
    k_prep_wlT  <<<128, 256, 0, stream>>>(W_leaf, WlT);
    k_prep_table<<<64, 256, 0, stream>>>(char_emb, W_x, b_x, b_child, WpT);
    k_prep_nodes<<<(NNODES + 31) / 32, 256, 0, stream>>>(node_emb, WlT, b_leaf, c_tab, h_tab);

    k_lo   <<<1024, 256, 0, stream>>>(c_tab, h_tab, leaf_idx, op_idx, WpT, g2c, g2h);
    k_level<<<256, 512, 0, stream>>>(g2c, g2h, g3c, g3h, WpT, op_idx, 1792, 7);  // L3
    k_level<<<128, 512, 0, stream>>>(g3c, g3h, g4c, g4h, WpT, op_idx, 1920, 6);  // L4
    k_level<<< 64, 512, 0, stream>>>(g4c, g4h, g5c, g5h, WpT, op_idx, 1984, 5);  // L5
    k_deep <<< 64, 512, 0, stream>>>(g5c, g5h, op_idx, WpT, W_and, b_and, c2, h2);
    k_final<<<1, 128, 0, stream>>>(c2, h2, init_emb, W_oend, b_oend, out);
}

// Round 8
// 411.596 us; speedup vs baseline: 1.2245x; 1.2245x over previous
//
#include <hip/hip_runtime.h>

#define NNODES 50000

typedef _Float16 half8 __attribute__((ext_vector_type(8)));
typedef float f32x4 __attribute__((ext_vector_type(4)));

__device__ __forceinline__ float sigm(float x)   { return 1.f / (1.f + __expf(-x)); }
__device__ __forceinline__ float tanh_f(float x) { float e = __expf(2.f * x); return 1.f - 2.f / (e + 1.f); }

// ---------------------------------------------------------------------------
// WpT[512 cols][288 k] fp16. k<128: W_child[2g][k][d]; k<256: W_child[2g+1][k-128][d]
// (col c -> gate g=c>>7, d=c&127). k in 256..287 filled by k_prep_table (op tab).
__global__ __launch_bounds__(256) void k_prep_wpT(const float* __restrict__ Wc,
                                                  _Float16* __restrict__ WpT) {
    int i = blockIdx.x * 256 + threadIdx.x;      // 0..131071
    int c = i >> 8, k = i & 255;
    int g = c >> 7, d = c & 127;
    float v = (k < 128) ? Wc[(2 * g) * 16384 + k * 128 + d]
                        : Wc[(2 * g + 1) * 16384 + (k - 128) * 128 + d];
    WpT[c * 288 + k] = (_Float16)v;
}

// tab rows of WpT: WpT[c*288 + 256 + t] = char_emb[t]@W_x[gx] + b_x[gx] + b_child[2g] + b_child[2g+1]
__global__ __launch_bounds__(256) void k_prep_table(const float* __restrict__ ce,
                                                    const float* __restrict__ Wx,
                                                    const float* __restrict__ bx,
                                                    const float* __restrict__ bc,
                                                    _Float16* __restrict__ WpT) {
    int i = blockIdx.x * 256 + threadIdx.x;      // 0..16383
    int tt = i >> 9, c = i & 511;
    int g = c >> 7, d = c & 127;
    int gx = (g == 0) ? 0 : ((g == 3) ? 2 : 1);
    float acc = bx[gx * 128 + d] + bc[(2 * g) * 128 + d] + bc[(2 * g + 1) * 128 + d];
    const float* x = ce + tt * 128;
    const float* w = Wx + gx * 16384 + d;
    for (int l = 0; l < 128; ++l) acc += x[l] * w[l * 128];
    WpT[c * 288 + 256 + tt] = (_Float16)acc;
}

// WlT[256 cols][128 k] fp16
__global__ __launch_bounds__(256) void k_prep_wlT(const float* __restrict__ Wl,
                                                  _Float16* __restrict__ WlT) {
    int i = blockIdx.x * 256 + threadIdx.x;      // 0..32767
    int c = i >> 7, k = i & 127;
    WlT[i] = (_Float16)Wl[(c >> 7) * 16384 + k * 128 + (c & 127)];
}

// ---------------------------------------------------------------------------
// Leaf tables: [50000 x 128] fp32 -> c_tab fp16, h_tab fp16 via f16 MFMA
__global__ __launch_bounds__(256) void k_prep_nodes(const float* __restrict__ ne,
                                                    const _Float16* __restrict__ WlT,
                                                    const float* __restrict__ bl,
                                                    _Float16* __restrict__ c_tab,
                                                    _Float16* __restrict__ h_tab) {
    const int t = threadIdx.x;
    const int w = t >> 6, l = t & 63;
    const int lr = l & 15, lq = l >> 4;
    const int nb = blockIdx.x * 32;

    int arow[2];
#pragma unroll
    for (int rt = 0; rt < 2; ++rt) {
        int r = nb + rt * 16 + lr;
        arow[rt] = (r < NNODES) ? r : (NNODES - 1);
    }

    f32x4 acc[2][2][2];
#pragma unroll
    for (int rt = 0; rt < 2; ++rt)
#pragma unroll
        for (int g = 0; g < 2; ++g)
#pragma unroll
            for (int ti = 0; ti < 2; ++ti) acc[rt][g][ti] = (f32x4)0.f;

#pragma unroll
    for (int kk = 0; kk < 4; ++kk) {
        half8 af[2];
#pragma unroll
        for (int rt = 0; rt < 2; ++rt) {
            const float* src = ne + (size_t)arow[rt] * 128 + kk * 32 + lq * 8;
            float4 f0 = *(const float4*)src;
            float4 f1 = *(const float4*)(src + 4);
            half8 v;
            v[0] = (_Float16)f0.x; v[1] = (_Float16)f0.y; v[2] = (_Float16)f0.z; v[3] = (_Float16)f0.w;
            v[4] = (_Float16)f1.x; v[5] = (_Float16)f1.y; v[6] = (_Float16)f1.z; v[7] = (_Float16)f1.w;
            af[rt] = v;
        }
#pragma unroll
        for (int g = 0; g < 2; ++g)
#pragma unroll
            for (int ti = 0; ti < 2; ++ti) {
                int col = g * 128 + w * 32 + ti * 16 + lr;
                half8 bb = *(const half8*)(WlT + col * 128 + kk * 32 + lq * 8);
#pragma unroll
                for (int rt = 0; rt < 2; ++rt)
                    acc[rt][g][ti] = __builtin_amdgcn_mfma_f32_16x16x32_f16(af[rt], bb, acc[rt][g][ti], 0, 0, 0);
            }
    }

#pragma unroll
    for (int rt = 0; rt < 2; ++rt)
#pragma unroll
        for (int j = 0; j < 4; ++j) {
            int r = nb + rt * 16 + lq * 4 + j;
            if (r < NNODES) {
#pragma unroll
                for (int ti = 0; ti < 2; ++ti) {
                    int d = w * 32 + ti * 16 + lr;
                    float cc = acc[rt][0][ti][j] + bl[d];
                    float hp = acc[rt][1][ti][j] + bl[128 + d];
                    c_tab[(size_t)r * 128 + d] = (_Float16)cc;
                    h_tab[(size_t)r * 128 + d] = (_Float16)(sigm(hp) * tanh_f(cc));
                }
            }
        }
}

// ---------------------------------------------------------------------------
// k_lo: levels 0-2 fused. 1024 blocks x 256 threads (4 waves x 32-col slices).
// Register discipline (r5-r7 lesson: NEVER cap below natural usage):
// L0 = four 16-pair quarter passes, L1 = two 16-pair passes -> acc stays at
// 32 AGPR; no prefetch arrays; lc/rc via early scalar gathers. Natural
// unified ~110-130 -> 3-4 blocks/CU at cap 256 (launch_bounds(256,2)).
// LDS ~34 KB (4 blocks/CU by LDS).
__global__ __launch_bounds__(256, 2) void k_lo(const _Float16* __restrict__ c_tab,
                                               const _Float16* __restrict__ h_tab,
                                               const int* __restrict__ leaf_idx,
                                               const int* __restrict__ op_idx,
                                               const _Float16* __restrict__ WpT,
                                               float* __restrict__ g2c,
                                               _Float16* __restrict__ g2h) {
    __shared__ int s_leaf[128];
    __shared__ int s_op[112];
    __shared__ _Float16 s_h0[64 * 128];     // swizzled; rows 0-31 reused for L1 out
    __shared__ _Float16 s_c0[64 * 132];     // rows 0-31 reused for L1 out

    const int t = threadIdx.x;
    const int w = t >> 6, l = t & 63, lr = l & 15, lq = l >> 4;
    const int ks = blockIdx.x >> 4, seg = blockIdx.x & 15;

    if (t < 128) s_leaf[t] = leaf_idx[ks * 2048 + seg * 128 + t];
    else if (t < 192) s_op[t - 128] = op_idx[ks * 2047 + seg * 64 + (t - 128)];
    else if (t < 224) s_op[64 + t - 192] = op_idx[ks * 2047 + 1024 + seg * 32 + (t - 192)];
    else if (t < 240) s_op[96 + t - 224] = op_idx[ks * 2047 + 1536 + seg * 16 + (t - 224)];
    __syncthreads();

    // ---- level 0: four 16-pair quarter passes (no barriers between them;
    //      each thread writes only its own output rows) ----
#pragma unroll 1
    for (int q = 0; q < 4; ++q) {
        // early lc/rc scalar gathers for this quarter's epilogue (8 regs)
        _Float16 lcv[2][4], rcv[2][4];
#pragma unroll
        for (int j = 0; j < 4; ++j) {
            int p = q * 16 + lq * 4 + j;
            int rl = s_leaf[2 * p], rr = s_leaf[2 * p + 1];
#pragma unroll
            for (int ti = 0; ti < 2; ++ti) {
                int d = w * 32 + ti * 16 + lr;
                lcv[ti][j] = c_tab[(size_t)rl * 128 + d];
                rcv[ti][j] = c_tab[(size_t)rr * 128 + d];
            }
        }

        const int pg = q * 16 + lr;          // A-fragment pair (row = lane&15)
        const int gl = s_leaf[2 * pg], gr = s_leaf[2 * pg + 1];
        const int opv = s_op[pg];

        f32x4 acc[4][2];
#pragma unroll
        for (int g = 0; g < 4; ++g)
#pragma unroll
            for (int ti = 0; ti < 2; ++ti) acc[g][ti] = (f32x4)0.f;

#pragma unroll
        for (int kk = 0; kk < 9; ++kk) {
            half8 a;
            if (kk < 8) {
                int row = (kk < 4) ? gl : gr;
                a = *(const half8*)(h_tab + (size_t)row * 128 + (kk & 3) * 32 + lq * 8);
            } else {
#pragma unroll
                for (int i = 0; i < 8; ++i)
                    a[i] = (_Float16)((lq * 8 + i) == opv ? 1.f : 0.f);
            }
#pragma unroll
            for (int g = 0; g < 4; ++g)
#pragma unroll
                for (int ti = 0; ti < 2; ++ti) {
                    half8 bb = *(const half8*)(WpT + (g * 128 + w * 32 + ti * 16 + lr) * 288 + kk * 32 + lq * 8);
                    acc[g][ti] = __builtin_amdgcn_mfma_f32_16x16x32_f16(a, bb, acc[g][ti], 0, 0, 0);
                }
        }

        // epilogue: own-row LDS writes, no barrier needed
#pragma unroll
        for (int j = 0; j < 4; ++j) {
            int p = q * 16 + lq * 4 + j;
#pragma unroll
            for (int ti = 0; ti < 2; ++ti) {
                int d = w * 32 + ti * 16 + lr;
                float vi = acc[0][ti][j], vl = acc[1][ti][j];
                float vr = acc[2][ti][j], vu = acc[3][ti][j];
                float cc = sigm(vi) * tanh_f(vu) + sigm(vl) * (float)lcv[ti][j]
                         + sigm(vr) * (float)rcv[ti][j];
                s_c0[p * 132 + d] = (_Float16)cc;
                s_h0[p * 128 + (d ^ ((p & 15) << 3))] = (_Float16)tanh_f(cc);
            }
        }
    }
    __syncthreads();   // h0/c0 (64 rows) complete

    // ---- level 1: two 16-pair passes; outputs overwrite rows 0..31 ----
#pragma unroll 1
    for (int p01 = 0; p01 < 2; ++p01) {
        const int pl = p01 * 16 + lr;        // A-fragment pair
        const int opv1 = s_op[64 + pl];

        f32x4 acc[4][2];
#pragma unroll
        for (int g = 0; g < 4; ++g)
#pragma unroll
            for (int ti = 0; ti < 2; ++ti) acc[g][ti] = (f32x4)0.f;

#pragma unroll
        for (int kk = 0; kk < 9; ++kk) {
            half8 a;
            if (kk < 8) {
                int side = kk >> 2, ko = (kk & 3) * 32 + lq * 8;
                int child = 2 * pl + side;   // rows [32*p01, 32*p01+32)
                a = *(const half8*)(s_h0 + child * 128 + (ko ^ ((child & 15) << 3)));
            } else {
#pragma unroll
                for (int i = 0; i < 8; ++i)
                    a[i] = (_Float16)((lq * 8 + i) == opv1 ? 1.f : 0.f);
            }
#pragma unroll
            for (int g = 0; g < 4; ++g)
#pragma unroll
                for (int ti = 0; ti < 2; ++ti) {
                    half8 bb = *(const half8*)(WpT + (g * 128 + w * 32 + ti * 16 + lr) * 288 + kk * 32 + lq * 8);
                    acc[g][ti] = __builtin_amdgcn_mfma_f32_16x16x32_f16(a, bb, acc[g][ti], 0, 0, 0);
                }
        }

        // read children-c to regs, then (pass 0 only) barrier, then write
        _Float16 lcv[2][4], rcv[2][4];
#pragma unroll
        for (int j = 0; j < 4; ++j) {
            int p = p01 * 16 + lq * 4 + j;
#pragma unroll
            for (int ti = 0; ti < 2; ++ti) {
                int d = w * 32 + ti * 16 + lr;
                lcv[ti][j] = s_c0[(2 * p) * 132 + d];
                rcv[ti][j] = s_c0[(2 * p + 1) * 132 + d];
            }
        }
        if (p01 == 0) __syncthreads();   // writes to rows 0..15 overlap reads of 0..31

#pragma unroll
        for (int j = 0; j < 4; ++j) {
            int p = p01 * 16 + lq * 4 + j;
#pragma unroll
            for (int ti = 0; ti < 2; ++ti) {
                int d = w * 32 + ti * 16 + lr;
                float vi = acc[0][ti][j], vl = acc[1][ti][j];
                float vr = acc[2][ti][j], vu = acc[3][ti][j];
                float cc = sigm(vi) * tanh_f(vu) + sigm(vl) * (float)lcv[ti][j]
                         + sigm(vr) * (float)rcv[ti][j];
                s_c0[p * 132 + d] = (_Float16)cc;
                s_h0[p * 128 + (d ^ ((p & 15) << 3))] = (_Float16)tanh_f(cc);
            }
        }
    }
    __syncthreads();   // L1 rows 0..31 complete

    // ---- level 2: 16 pairs -> global ----
    const int opv2 = s_op[96 + lr];
    f32x4 acc2[4][2];
#pragma unroll
    for (int g = 0; g < 4; ++g)
#pragma unroll
        for (int ti = 0; ti < 2; ++ti) acc2[g][ti] = (f32x4)0.f;

#pragma unroll
    for (int kk = 0; kk < 9; ++kk) {
        half8 a;
        if (kk < 8) {
            int side = kk >> 2, ko = (kk & 3) * 32 + lq * 8;
            int child = 2 * lr + side;
            a = *(const half8*)(s_h0 + child * 128 + (ko ^ ((child & 15) << 3)));
        } else {
#pragma unroll
            for (int i = 0; i < 8; ++i)
                a[i] = (_Float16)((lq * 8 + i) == opv2 ? 1.f : 0.f);
        }
#pragma unroll
        for (int g = 0; g < 4; ++g)
#pragma unroll
            for (int ti = 0; ti < 2; ++ti) {
                half8 bb = *(const half8*)(WpT + (g * 128 + w * 32 + ti * 16 + lr) * 288 + kk * 32 + lq * 8);
                acc2[g][ti] = __builtin_amdgcn_mfma_f32_16x16x32_f16(a, bb, acc2[g][ti], 0, 0, 0);
            }
    }

#pragma unroll
    for (int j = 0; j < 4; ++j) {
        int p = lq * 4 + j;
#pragma unroll
        for (int ti = 0; ti < 2; ++ti) {
            int d = w * 32 + ti * 16 + lr;
            float vi = acc2[0][ti][j], vl = acc2[1][ti][j];
            float vr = acc2[2][ti][j], vu = acc2[3][ti][j];
            float lc = (float)s_c0[(2 * p) * 132 + d];
            float rc = (float)s_c0[(2 * p + 1) * 132 + d];
            float cc = sigm(vi) * tanh_f(vu) + sigm(vl) * lc + sigm(vr) * rc;
            size_t orow = (size_t)blockIdx.x * 16 + p;
            g2c[orow * 128 + d] = cc;
            g2h[orow * 128 + d] = (_Float16)tanh_f(cc);
        }
    }
}

// ---------------------------------------------------------------------------
// Generic mid level: 32 pairs/block, 512 threads, no LDS. Children are
// contiguous rows 2p,2p+1 of the previous level's dense output.
__global__ __launch_bounds__(512, 4) void k_level(const float* __restrict__ c_src,
                                                  const _Float16* __restrict__ h_src,
                                                  float* __restrict__ c_dst,
                                                  _Float16* __restrict__ h_dst,
                                                  const _Float16* __restrict__ WpT,
                                                  const int* __restrict__ op_idx,
                                                  int op_start, int mshift) {
    const int t = threadIdx.x;
    const int w = t >> 6, l = t & 63, lr = l & 15, lq = l >> 4;
    const int pbase = blockIdx.x * 32;

    int opv[2];
#pragma unroll
    for (int rt = 0; rt < 2; ++rt) {
        int pg = pbase + rt * 16 + lr;
        int ksx = pg >> mshift, j = pg & ((1 << mshift) - 1);
        opv[rt] = op_idx[ksx * 2047 + op_start + j];
    }

    f32x4 acc[2][4];
#pragma unroll
    for (int rt = 0; rt < 2; ++rt)
#pragma unroll
        for (int g = 0; g < 4; ++g) acc[rt][g] = (f32x4)0.f;

#pragma unroll
    for (int kk = 0; kk < 9; ++kk) {
        half8 a[2];
        if (kk < 8) {
            int side = kk >> 2, ko = (kk & 3) * 32 + lq * 8;
#pragma unroll
            for (int rt = 0; rt < 2; ++rt) {
                int row = 2 * (pbase + rt * 16 + lr) + side;
                a[rt] = *(const half8*)(h_src + (size_t)row * 128 + ko);
            }
        } else {
#pragma unroll
            for (int rt = 0; rt < 2; ++rt)
#pragma unroll
                for (int i = 0; i < 8; ++i)
                    a[rt][i] = (_Float16)((lq * 8 + i) == opv[rt] ? 1.f : 0.f);
        }
#pragma unroll
        for (int g = 0; g < 4; ++g) {
            half8 bb = *(const half8*)(WpT + (g * 128 + w * 16 + lr) * 288 + kk * 32 + lq * 8);
#pragma unroll
            for (int rt = 0; rt < 2; ++rt)
                acc[rt][g] = __builtin_amdgcn_mfma_f32_16x16x32_f16(a[rt], bb, acc[rt][g], 0, 0, 0);
        }
    }

    const int d = w * 16 + lr;
#pragma unroll
    for (int rt = 0; rt < 2; ++rt)
#pragma unroll
        for (int j = 0; j < 4; ++j) {
            int p = pbase + rt * 16 + lq * 4 + j;
            float vi = acc[rt][0][j], vl = acc[rt][1][j], vr = acc[rt][2][j], vu = acc[rt][3][j];
            float lc = c_src[(size_t)(2 * p) * 128 + d];
            float rc = c_src[(size_t)(2 * p + 1) * 128 + d];
            float cc = sigm(vi) * tanh_f(vu) + sigm(vl) * lc + sigm(vr) * rc;
            c_dst[(size_t)p * 128 + d] = cc;
            h_dst[(size_t)p * 128 + d] = (_Float16)tanh_f(cc);
        }
}

// ---------------------------------------------------------------------------
// k_deep: levels 6-10 + AND projection. One block per tree, WpT held in regs.
template <bool GSRC>
__device__ __forceinline__ void deep_pass(int np, int opoff,
                                          const _Float16* hS, const _Float16* cS,
                                          const _Float16* __restrict__ gh,
                                          const float* __restrict__ gc, int rowbase,
                                          _Float16* hD, _Float16* cD,
                                          const half8 (&B)[9][4],
                                          const int* s_op, int w, int lq, int lr) {
    f32x4 acc[4];
#pragma unroll
    for (int g = 0; g < 4; ++g) acc[g] = (f32x4)0.f;
    int pidx = lr < np ? lr : np - 1;
    int op = s_op[opoff + pidx];
#pragma unroll
    for (int kk = 0; kk < 9; ++kk) {
        half8 a;
        if (kk < 8) {
            int side = kk >> 2, ko = (kk & 3) * 32 + lq * 8;
            int child = 2 * pidx + side;
            if constexpr (GSRC)
                a = *(const half8*)(gh + (size_t)(rowbase + child) * 128 + ko);
            else
                a = *(const half8*)(hS + child * 128 + (ko ^ ((child & 15) << 3)));
        } else {
#pragma unroll
            for (int i = 0; i < 8; ++i)
                a[i] = (_Float16)((lq * 8 + i) == op ? 1.f : 0.f);
        }
#pragma unroll
        for (int g = 0; g < 4; ++g)
            acc[g] = __builtin_amdgcn_mfma_f32_16x16x32_f16(a, B[kk][g], acc[g], 0, 0, 0);
    }
    const int d = w * 16 + lr;
#pragma unroll
    for (int j = 0; j < 4; ++j) {
        int p = lq * 4 + j;
        if (p < np) {
            float vi = acc[0][j], vl = acc[1][j], vr = acc[2][j], vu = acc[3][j];
            float lc, rc;
            if constexpr (GSRC) {
                lc = gc[(size_t)(rowbase + 2 * p) * 128 + d];
                rc = gc[(size_t)(rowbase + 2 * p + 1) * 128 + d];
            } else {
                lc = (float)cS[(2 * p) * 132 + d];
                rc = (float)cS[(2 * p + 1) * 132 + d];
            }
            float cc = sigm(vi) * tanh_f(vu) + sigm(vl) * lc + sigm(vr) * rc;
            cD[p * 132 + d] = (_Float16)cc;
            hD[p * 128 + (d ^ ((p & 15) << 3))] = (_Float16)tanh_f(cc);
        }
    }
}

__global__ __launch_bounds__(512, 2) void k_deep(const float* __restrict__ g5c,
                                                 const _Float16* __restrict__ g5h,
                                                 const int* __restrict__ op_idx,
                                                 const _Float16* __restrict__ WpT,
                                                 const float* __restrict__ Wa,
                                                 const float* __restrict__ ba,
                                                 float* __restrict__ c2,
                                                 float* __restrict__ h2) {
    __shared__ int s_op[32];
    __shared__ _Float16 hA[16 * 128], cA[16 * 132];
    __shared__ _Float16 hB[8 * 128],  cB[8 * 132];
    const int t = threadIdx.x, w = t >> 6, l = t & 63, lr = l & 15, lq = l >> 4;
    const int tree = blockIdx.x;

    if (t < 31) s_op[t] = op_idx[tree * 2047 + 2016 + t];   // L6:0..15 L7:16..23 L8:24..27 L9:28..29 L10:30
    __syncthreads();

    half8 B[9][4];
#pragma unroll
    for (int kk = 0; kk < 9; ++kk)
#pragma unroll
        for (int g = 0; g < 4; ++g)
            B[kk][g] = *(const half8*)(WpT + (g * 128 + w * 16 + lr) * 288 + kk * 32 + lq * 8);

    deep_pass<true >(16,  0, nullptr, nullptr, g5h, g5c, tree * 32, hA, cA, B, s_op, w, lq, lr);
    __syncthreads();
    deep_pass<false>( 8, 16, hA, cA, nullptr, nullptr, 0, hB, cB, B, s_op, w, lq, lr);
    __syncthreads();
    deep_pass<false>( 4, 24, hB, cB, nullptr, nullptr, 0, hA, cA, B, s_op, w, lq, lr);
    __syncthreads();
    deep_pass<false>( 2, 28, hA, cA, nullptr, nullptr, 0, hB, cB, B, s_op, w, lq, lr);
    __syncthreads();
    deep_pass<false>( 1, 30, hB, cB, nullptr, nullptr, 0, hA, cA, B, s_op, w, lq, lr);
    __syncthreads();

    // AND projection (root = row 0 of A; p=0 swizzle is identity)
    if (t < 256) {
        int dd = t & 127;
        if (t < 128) {
            float a = ba[dd];
            for (int ll = 0; ll < 128; ++ll) a += (float)cA[ll] * Wa[ll * 128 + dd];
            c2[tree * 128 + dd] = a;
        } else {
            float a = ba[128 + dd];
            for (int ll = 0; ll < 128; ++ll) a += (float)hA[ll] * Wa[16384 + ll * 128 + dd];
            h2[tree * 128 + dd] = a;
        }
    }
}

// ---------------------------------------------------------------------------
__global__ __launch_bounds__(128) void k_final(const float* __restrict__ c2,
                                               const float* __restrict__ h2,
                                               const float* __restrict__ init_e,
                                               const float* __restrict__ Wo,
                                               const float* __restrict__ bo,
                                               float* __restrict__ out) {
    __shared__ float s[384];
    const int d = threadIdx.x;
    float cm = c2[d], hm = h2[d];
    for (int k = 1; k < 64; ++k) {
        cm = fminf(cm, c2[k * 128 + d]);
        hm = fminf(hm, h2[k * 128 + d]);
    }
    s[d] = init_e[d];
    s[128 + d] = cm;
    s[256 + d] = hm;
    __syncthreads();
    float a = bo[d];
    for (int l = 0; l < 384; ++l) a += s[l] * Wo[l * 128 + d];
    out[d] = tanhf(a);
}

// ---------------------------------------------------------------------------
extern "C" void kernel_launch(void* const* d_in, const int* in_sizes, int n_in,
                              void* d_out, int out_size, void* d_ws, size_t ws_size,
                              hipStream_t stream) {
    const float* node_emb = (const float*)d_in[0];
    const float* init_emb = (const float*)d_in[1];
    const float* char_emb = (const float*)d_in[2];
    const float* W_child  = (const float*)d_in[3];
    const float* b_child  = (const float*)d_in[4];
    const float* W_x      = (const float*)d_in[5];
    const float* b_x      = (const float*)d_in[6];
    const float* W_leaf   = (const float*)d_in[7];
    const float* b_leaf   = (const float*)d_in[8];
    const float* W_and    = (const float*)d_in[9];
    const float* b_and    = (const float*)d_in[10];
    const float* W_oend   = (const float*)d_in[11];
    const float* b_oend   = (const float*)d_in[12];
    const int* leaf_idx   = (const int*)d_in[13];
    const int* op_idx     = (const int*)d_in[14];
    float* out = (float*)d_out;
    (void)in_sizes; (void)n_in; (void)out_size; (void)ws_size;

    char* p = (char*)d_ws;
    auto carve = [&](size_t bytes) { char* r = p; p += (bytes + 255) & ~255ull; return r; };
    _Float16* WpT   = (_Float16*)carve((size_t)512 * 288 * 2);
    _Float16* WlT   = (_Float16*)carve((size_t)256 * 128 * 2);
    _Float16* c_tab = (_Float16*)carve((size_t)NNODES * 128 * 2);
    _Float16* h_tab = (_Float16*)carve((size_t)NNODES * 128 * 2);
    float*    g2c   = (float*)carve((size_t)16384 * 128 * 4);
    _Float16* g2h   = (_Float16*)carve((size_t)16384 * 128 * 2);
    float*    g3c   = (float*)carve((size_t)8192 * 128 * 4);
    _Float16* g3h   = (_Float16*)carve((size_t)8192 * 128 * 2);
    float*    g4c   = (float*)carve((size_t)4096 * 128 * 4);
    _Float16* g4h   = (_Float16*)carve((size_t)4096 * 128 * 2);
    float*    g5c   = (float*)carve((size_t)2048 * 128 * 4);
    _Float16* g5h   = (_Float16*)carve((size_t)2048 * 128 * 2);
    float*    c2    = (float*)carve(64 * 128 * 4);
    float*    h2    = (float*)carve(64 * 128 * 4);

    k_prep_wpT  <<<512, 256, 0, stream>>>(W_child, WpT);
    k_prep_wlT  <<<128, 256, 0, stream>>>(W_leaf, WlT);
    k_prep_table<<<64, 256, 0, stream>>>(char_emb, W_x, b_x, b_child, WpT);
    k_prep_nodes<<<(NNODES + 31) / 32, 256, 0, stream>>>(node_emb, WlT, b_leaf, c_tab, h_tab);

    k_lo   <<<1024, 256, 0, stream>>>(c_tab, h_tab, leaf_idx, op_idx, WpT, g2c, g2h);
    k_level<<<256, 512, 0, stream>>>(g2c, g2h, g3c, g3h, WpT, op_idx, 1792, 7);  // L3
    k_level<<<128, 512, 0, stream>>>(g3c, g3h, g4c, g4h, WpT, op_idx, 1920, 6);  // L4
    k_level<<< 64, 512, 0, stream>>>(g4c, g4h, g5c, g5h, WpT, op_idx, 1984, 5);  // L5
    k_deep <<< 64, 512, 0, stream>>>(g5c, g5h, op_idx, WpT, W_and, b_and, c2, h2);
    k_final<<<1, 128, 0, stream>>>(c2, h2, init_emb, W_oend, b_oend, out);
}

// Round 9
// 224.775 us; speedup vs baseline: 2.2422x; 1.8311x over previous
//
#include <hip/hip_runtime.h>

#define NNODES 50000

typedef _Float16 half8 __attribute__((ext_vector_type(8)));
typedef float f32x4 __attribute__((ext_vector_type(4)));

__device__ __forceinline__ float sigm(float x)   { return 1.f / (1.f + __expf(-x)); }
__device__ __forceinline__ float tanh_f(float x) { float e = __expf(2.f * x); return 1.f - 2.f / (e + 1.f); }

// ---------------------------------------------------------------------------
// WpT[512 cols][288 k] fp16. k<128: W_child[2g][k][d]; k<256: W_child[2g+1][k-128][d]
// (col c -> gate g=c>>7, d=c&127). k in 256..287 filled by k_prep_table (op tab).
__global__ __launch_bounds__(256) void k_prep_wpT(const float* __restrict__ Wc,
                                                  _Float16* __restrict__ WpT) {
    int i = blockIdx.x * 256 + threadIdx.x;      // 0..131071
    int c = i >> 8, k = i & 255;
    int g = c >> 7, d = c & 127;
    float v = (k < 128) ? Wc[(2 * g) * 16384 + k * 128 + d]
                        : Wc[(2 * g + 1) * 16384 + (k - 128) * 128 + d];
    WpT[c * 288 + k] = (_Float16)v;
}

// tab rows of WpT: WpT[c*288 + 256 + t] = char_emb[t]@W_x[gx] + b_x[gx] + b_child[2g] + b_child[2g+1]
__global__ __launch_bounds__(256) void k_prep_table(const float* __restrict__ ce,
                                                    const float* __restrict__ Wx,
                                                    const float* __restrict__ bx,
                                                    const float* __restrict__ bc,
                                                    _Float16* __restrict__ WpT) {
    int i = blockIdx.x * 256 + threadIdx.x;      // 0..16383
    int tt = i >> 9, c = i & 511;
    int g = c >> 7, d = c & 127;
    int gx = (g == 0) ? 0 : ((g == 3) ? 2 : 1);
    float acc = bx[gx * 128 + d] + bc[(2 * g) * 128 + d] + bc[(2 * g + 1) * 128 + d];
    const float* x = ce + tt * 128;
    const float* w = Wx + gx * 16384 + d;
    for (int l = 0; l < 128; ++l) acc += x[l] * w[l * 128];
    WpT[c * 288 + 256 + tt] = (_Float16)acc;
}

// WlT[256 cols][128 k] fp16
__global__ __launch_bounds__(256) void k_prep_wlT(const float* __restrict__ Wl,
                                                  _Float16* __restrict__ WlT) {
    int i = blockIdx.x * 256 + threadIdx.x;      // 0..32767
    int c = i >> 7, k = i & 127;
    WlT[i] = (_Float16)Wl[(c >> 7) * 16384 + k * 128 + (c & 127)];
}

// ---------------------------------------------------------------------------
// Leaf tables: [50000 x 128] fp32 -> c_tab fp16, h_tab fp16 via f16 MFMA
__global__ __launch_bounds__(256) void k_prep_nodes(const float* __restrict__ ne,
                                                    const _Float16* __restrict__ WlT,
                                                    const float* __restrict__ bl,
                                                    _Float16* __restrict__ c_tab,
                                                    _Float16* __restrict__ h_tab) {
    const int t = threadIdx.x;
    const int w = t >> 6, l = t & 63;
    const int lr = l & 15, lq = l >> 4;
    const int nb = blockIdx.x * 32;

    int arow[2];
#pragma unroll
    for (int rt = 0; rt < 2; ++rt) {
        int r = nb + rt * 16 + lr;
        arow[rt] = (r < NNODES) ? r : (NNODES - 1);
    }

    f32x4 acc[2][2][2];
#pragma unroll
    for (int rt = 0; rt < 2; ++rt)
#pragma unroll
        for (int g = 0; g < 2; ++g)
#pragma unroll
            for (int ti = 0; ti < 2; ++ti) acc[rt][g][ti] = (f32x4)0.f;

#pragma unroll
    for (int kk = 0; kk < 4; ++kk) {
        half8 af[2];
#pragma unroll
        for (int rt = 0; rt < 2; ++rt) {
            const float* src = ne + (size_t)arow[rt] * 128 + kk * 32 + lq * 8;
            float4 f0 = *(const float4*)src;
            float4 f1 = *(const float4*)(src + 4);
            half8 v;
            v[0] = (_Float16)f0.x; v[1] = (_Float16)f0.y; v[2] = (_Float16)f0.z; v[3] = (_Float16)f0.w;
            v[4] = (_Float16)f1.x; v[5] = (_Float16)f1.y; v[6] = (_Float16)f1.z; v[7] = (_Float16)f1.w;
            af[rt] = v;
        }
#pragma unroll
        for (int g = 0; g < 2; ++g)
#pragma unroll
            for (int ti = 0; ti < 2; ++ti) {
                int col = g * 128 + w * 32 + ti * 16 + lr;
                half8 bb = *(const half8*)(WlT + col * 128 + kk * 32 + lq * 8);
#pragma unroll
                for (int rt = 0; rt < 2; ++rt)
                    acc[rt][g][ti] = __builtin_amdgcn_mfma_f32_16x16x32_f16(af[rt], bb, acc[rt][g][ti], 0, 0, 0);
            }
    }

#pragma unroll
    for (int rt = 0; rt < 2; ++rt)
#pragma unroll
        for (int j = 0; j < 4; ++j) {
            int r = nb + rt * 16 + lq * 4 + j;
            if (r < NNODES) {
#pragma unroll
                for (int ti = 0; ti < 2; ++ti) {
                    int d = w * 32 + ti * 16 + lr;
                    float cc = acc[rt][0][ti][j] + bl[d];
                    float hp = acc[rt][1][ti][j] + bl[128 + d];
                    c_tab[(size_t)r * 128 + d] = (_Float16)cc;
                    h_tab[(size_t)r * 128 + d] = (_Float16)(sigm(hp) * tanh_f(cc));
                }
            }
        }
}

// ---------------------------------------------------------------------------
// k_lo: levels 0-2 fused. 1024 blocks = 64 trees x 16 segs; block owns
// 64 L0-pairs -> 32 L1 -> 16 L2 outputs. Level 0 in two HAND-UNROLLED
// 32-pair half-passes with register-staged gathers.
// NOTE (r5-r8 post-mortem): do NOT wrap the half-passes in a `#pragma
// unroll 1` loop — the WpT B-fragment loads are loop-invariant and LICM
// hoists ~288 VGPRs of them, causing catastrophic scratch spill. The
// hand-unrolled form (this one) measured 120 us, VGPR 120, zero spill (r4).
__global__ __launch_bounds__(256, 2) void k_lo(const _Float16* __restrict__ c_tab,
                                               const _Float16* __restrict__ h_tab,
                                               const int* __restrict__ leaf_idx,
                                               const int* __restrict__ op_idx,
                                               const _Float16* __restrict__ WpT,
                                               float* __restrict__ g2c,
                                               _Float16* __restrict__ g2h) {
    __shared__ int s_leaf[128];
    __shared__ int s_op[112];
    __shared__ _Float16 s_cst[64 * 132];    // staged child-c rows (one half); reused as h1|c1
    __shared__ _Float16 s_h0[64 * 128];     // swizzled
    __shared__ _Float16 s_c0[64 * 132];
    _Float16* s_h1 = s_cst;                 // 32*128
    _Float16* s_c1 = s_cst + 32 * 128;      // 32*132 (8320 <= 8448)

    const int t = threadIdx.x;
    const int w = t >> 6, l = t & 63, lr = l & 15, lq = l >> 4;
    const int ks = blockIdx.x >> 4, seg = blockIdx.x & 15;
    const int crow = t >> 2, coff = (t & 3) * 32;

    if (t < 128) s_leaf[t] = leaf_idx[ks * 2048 + seg * 128 + t];
    else if (t < 192) s_op[t - 128] = op_idx[ks * 2047 + seg * 64 + (t - 128)];
    else if (t < 224) s_op[64 + t - 192] = op_idx[ks * 2047 + 1024 + seg * 32 + (t - 192)];
    else if (t < 240) s_op[96 + t - 224] = op_idx[ks * 2047 + 1536 + seg * 16 + (t - 224)];
    __syncthreads();

    // ---- half 0: issue c-stage + A-gathers into registers ----
    half8 cr0[4];
    {
        const _Float16* src = c_tab + (size_t)s_leaf[crow] * 128 + coff;
#pragma unroll
        for (int i = 0; i < 4; ++i) cr0[i] = *(const half8*)(src + i * 8);
    }
    int opv0[2];
    half8 af0[2][8];
#pragma unroll
    for (int rt = 0; rt < 2; ++rt) {
        int pg = rt * 16 + lr;
        int gl = s_leaf[2 * pg], gr = s_leaf[2 * pg + 1];
        opv0[rt] = s_op[pg];
#pragma unroll
        for (int kk = 0; kk < 8; ++kk) {
            int row = (kk < 4) ? gl : gr;
            af0[rt][kk] = *(const half8*)(h_tab + (size_t)row * 128 + (kk & 3) * 32 + lq * 8);
        }
    }

    // ---- GEMM half 0 ----
    f32x4 acc[2][4][2];
#pragma unroll
    for (int rt = 0; rt < 2; ++rt)
#pragma unroll
        for (int g = 0; g < 4; ++g)
#pragma unroll
            for (int ti = 0; ti < 2; ++ti) acc[rt][g][ti] = (f32x4)0.f;

#pragma unroll
    for (int kk = 0; kk < 9; ++kk) {
        half8 bb[4][2];
#pragma unroll
        for (int g = 0; g < 4; ++g)
#pragma unroll
            for (int ti = 0; ti < 2; ++ti)
                bb[g][ti] = *(const half8*)(WpT + (g * 128 + w * 32 + ti * 16 + lr) * 288 + kk * 32 + lq * 8);
        half8 a[2];
        if (kk < 8) {
            a[0] = af0[0][kk]; a[1] = af0[1][kk];
        } else {
#pragma unroll
            for (int rt = 0; rt < 2; ++rt)
#pragma unroll
                for (int i = 0; i < 8; ++i)
                    a[rt][i] = (_Float16)((lq * 8 + i) == opv0[rt] ? 1.f : 0.f);
        }
#pragma unroll
        for (int rt = 0; rt < 2; ++rt)
#pragma unroll
            for (int g = 0; g < 4; ++g)
#pragma unroll
                for (int ti = 0; ti < 2; ++ti)
                    acc[rt][g][ti] = __builtin_amdgcn_mfma_f32_16x16x32_f16(a[rt], bb[g][ti], acc[rt][g][ti], 0, 0, 0);
    }

    // ---- issue half-1 c-stage + A-gathers (latency hidden under epilogue 0) ----
    half8 cr1[4];
    {
        const _Float16* src = c_tab + (size_t)s_leaf[64 + crow] * 128 + coff;
#pragma unroll
        for (int i = 0; i < 4; ++i) cr1[i] = *(const half8*)(src + i * 8);
    }
    int opv1h[2];
    half8 af1[2][8];
#pragma unroll
    for (int rt = 0; rt < 2; ++rt) {
        int pg = 32 + rt * 16 + lr;
        int gl = s_leaf[2 * pg], gr = s_leaf[2 * pg + 1];
        opv1h[rt] = s_op[pg];
#pragma unroll
        for (int kk = 0; kk < 8; ++kk) {
            int row = (kk < 4) ? gl : gr;
            af1[rt][kk] = *(const half8*)(h_tab + (size_t)row * 128 + (kk & 3) * 32 + lq * 8);
        }
    }

    // ---- write cst0 (loads long since landed), epilogue 0 ----
#pragma unroll
    for (int i = 0; i < 4; ++i) *(half8*)(s_cst + crow * 132 + coff + i * 8) = cr0[i];
    __syncthreads();

#pragma unroll
    for (int rt = 0; rt < 2; ++rt)
#pragma unroll
        for (int j = 0; j < 4; ++j) {
            int pl = rt * 16 + lq * 4 + j;        // == global pair for half 0
#pragma unroll
            for (int ti = 0; ti < 2; ++ti) {
                int d = w * 32 + ti * 16 + lr;
                float vi = acc[rt][0][ti][j], vl = acc[rt][1][ti][j];
                float vr = acc[rt][2][ti][j], vu = acc[rt][3][ti][j];
                float lc = (float)s_cst[(2 * pl) * 132 + d];
                float rc = (float)s_cst[(2 * pl + 1) * 132 + d];
                float cc = sigm(vi) * tanh_f(vu) + sigm(vl) * lc + sigm(vr) * rc;
                s_c0[pl * 132 + d] = (_Float16)cc;
                s_h0[pl * 128 + (d ^ ((pl & 15) << 3))] = (_Float16)tanh_f(cc);
            }
        }
    __syncthreads();   // s_cst reuse guard

    // ---- write cst1, GEMM half 1 ----
#pragma unroll
    for (int i = 0; i < 4; ++i) *(half8*)(s_cst + crow * 132 + coff + i * 8) = cr1[i];

#pragma unroll
    for (int rt = 0; rt < 2; ++rt)
#pragma unroll
        for (int g = 0; g < 4; ++g)
#pragma unroll
            for (int ti = 0; ti < 2; ++ti) acc[rt][g][ti] = (f32x4)0.f;

#pragma unroll
    for (int kk = 0; kk < 9; ++kk) {
        half8 bb[4][2];
#pragma unroll
        for (int g = 0; g < 4; ++g)
#pragma unroll
            for (int ti = 0; ti < 2; ++ti)
                bb[g][ti] = *(const half8*)(WpT + (g * 128 + w * 32 + ti * 16 + lr) * 288 + kk * 32 + lq * 8);
        half8 a[2];
        if (kk < 8) {
            a[0] = af1[0][kk]; a[1] = af1[1][kk];
        } else {
#pragma unroll
            for (int rt = 0; rt < 2; ++rt)
#pragma unroll
                for (int i = 0; i < 8; ++i)
                    a[rt][i] = (_Float16)((lq * 8 + i) == opv1h[rt] ? 1.f : 0.f);
        }
#pragma unroll
        for (int rt = 0; rt < 2; ++rt)
#pragma unroll
            for (int g = 0; g < 4; ++g)
#pragma unroll
                for (int ti = 0; ti < 2; ++ti)
                    acc[rt][g][ti] = __builtin_amdgcn_mfma_f32_16x16x32_f16(a[rt], bb[g][ti], acc[rt][g][ti], 0, 0, 0);
    }
    __syncthreads();   // cst1 visible to all

    // ---- epilogue 1 ----
#pragma unroll
    for (int rt = 0; rt < 2; ++rt)
#pragma unroll
        for (int j = 0; j < 4; ++j) {
            int pl = rt * 16 + lq * 4 + j;
            int pg = 32 + pl;
#pragma unroll
            for (int ti = 0; ti < 2; ++ti) {
                int d = w * 32 + ti * 16 + lr;
                float vi = acc[rt][0][ti][j], vl = acc[rt][1][ti][j];
                float vr = acc[rt][2][ti][j], vu = acc[rt][3][ti][j];
                float lc = (float)s_cst[(2 * pl) * 132 + d];
                float rc = (float)s_cst[(2 * pl + 1) * 132 + d];
                float cc = sigm(vi) * tanh_f(vu) + sigm(vl) * lc + sigm(vr) * rc;
                s_c0[pg * 132 + d] = (_Float16)cc;
                s_h0[pg * 128 + (d ^ ((pg & 15) << 3))] = (_Float16)tanh_f(cc);
            }
        }
    __syncthreads();   // h0/c0 complete; s_cst reads done -> h1/c1 alias safe

    // ---- level 1 (32 pairs) ----
#pragma unroll
    for (int rt = 0; rt < 2; ++rt)
#pragma unroll
        for (int g = 0; g < 4; ++g)
#pragma unroll
            for (int ti = 0; ti < 2; ++ti) acc[rt][g][ti] = (f32x4)0.f;

    int opv1[2];
    opv1[0] = s_op[64 + lr]; opv1[1] = s_op[80 + lr];

#pragma unroll
    for (int kk = 0; kk < 9; ++kk) {
        half8 bb[4][2];
#pragma unroll
        for (int g = 0; g < 4; ++g)
#pragma unroll
            for (int ti = 0; ti < 2; ++ti)
                bb[g][ti] = *(const half8*)(WpT + (g * 128 + w * 32 + ti * 16 + lr) * 288 + kk * 32 + lq * 8);
        half8 a[2];
        if (kk < 8) {
            int side = kk >> 2, ko = (kk & 3) * 32 + lq * 8;
#pragma unroll
            for (int rt = 0; rt < 2; ++rt) {
                int child = 2 * (rt * 16 + lr) + side;
                a[rt] = *(const half8*)(s_h0 + child * 128 + (ko ^ ((child & 15) << 3)));
            }
        } else {
#pragma unroll
            for (int rt = 0; rt < 2; ++rt)
#pragma unroll
                for (int i = 0; i < 8; ++i)
                    a[rt][i] = (_Float16)((lq * 8 + i) == opv1[rt] ? 1.f : 0.f);
        }
#pragma unroll
        for (int rt = 0; rt < 2; ++rt)
#pragma unroll
            for (int g = 0; g < 4; ++g)
#pragma unroll
                for (int ti = 0; ti < 2; ++ti)
                    acc[rt][g][ti] = __builtin_amdgcn_mfma_f32_16x16x32_f16(a[rt], bb[g][ti], acc[rt][g][ti], 0, 0, 0);
    }

#pragma unroll
    for (int rt = 0; rt < 2; ++rt)
#pragma unroll
        for (int j = 0; j < 4; ++j) {
            int pl = rt * 16 + lq * 4 + j;
#pragma unroll
            for (int ti = 0; ti < 2; ++ti) {
                int d = w * 32 + ti * 16 + lr;
                float vi = acc[rt][0][ti][j], vl = acc[rt][1][ti][j];
                float vr = acc[rt][2][ti][j], vu = acc[rt][3][ti][j];
                float lc = (float)s_c0[(2 * pl) * 132 + d];
                float rc = (float)s_c0[(2 * pl + 1) * 132 + d];
                float cc = sigm(vi) * tanh_f(vu) + sigm(vl) * lc + sigm(vr) * rc;
                s_c1[pl * 132 + d] = (_Float16)cc;
                s_h1[pl * 128 + (d ^ ((pl & 15) << 3))] = (_Float16)tanh_f(cc);
            }
        }
    __syncthreads();

    // ---- level 2 (16 pairs) -> global ----
    f32x4 acc2[4][2];
#pragma unroll
    for (int g = 0; g < 4; ++g)
#pragma unroll
        for (int ti = 0; ti < 2; ++ti) acc2[g][ti] = (f32x4)0.f;

    int opv2 = s_op[96 + lr];

#pragma unroll
    for (int kk = 0; kk < 9; ++kk) {
        half8 bb[4][2];
#pragma unroll
        for (int g = 0; g < 4; ++g)
#pragma unroll
            for (int ti = 0; ti < 2; ++ti)
                bb[g][ti] = *(const half8*)(WpT + (g * 128 + w * 32 + ti * 16 + lr) * 288 + kk * 32 + lq * 8);
        half8 a;
        if (kk < 8) {
            int side = kk >> 2, ko = (kk & 3) * 32 + lq * 8;
            int child = 2 * lr + side;
            a = *(const half8*)(s_h1 + child * 128 + (ko ^ ((child & 15) << 3)));
        } else {
#pragma unroll
            for (int i = 0; i < 8; ++i)
                a[i] = (_Float16)((lq * 8 + i) == opv2 ? 1.f : 0.f);
        }
#pragma unroll
        for (int g = 0; g < 4; ++g)
#pragma unroll
            for (int ti = 0; ti < 2; ++ti)
                acc2[g][ti] = __builtin_amdgcn_mfma_f32_16x16x32_f16(a, bb[g][ti], acc2[g][ti], 0, 0, 0);
    }

#pragma unroll
    for (int j = 0; j < 4; ++j) {
        int p = lq * 4 + j;
#pragma unroll
        for (int ti = 0; ti < 2; ++ti) {
            int d = w * 32 + ti * 16 + lr;
            float vi = acc2[0][ti][j], vl = acc2[1][ti][j];
            float vr = acc2[2][ti][j], vu = acc2[3][ti][j];
            float lc = (float)s_c1[(2 * p) * 132 + d];
            float rc = (float)s_c1[(2 * p + 1) * 132 + d];
            float cc = sigm(vi) * tanh_f(vu) + sigm(vl) * lc + sigm(vr) * rc;
            size_t orow = (size_t)blockIdx.x * 16 + p;
            g2c[orow * 128 + d] = cc;
            g2h[orow * 128 + d] = (_Float16)tanh_f(cc);
        }
    }
}

// ---------------------------------------------------------------------------
// Generic mid level: 32 pairs/block, 512 threads, no LDS. Children are
// contiguous rows 2p,2p+1 of the previous level's dense output.
__global__ __launch_bounds__(512, 4) void k_level(const float* __restrict__ c_src,
                                                  const _Float16* __restrict__ h_src,
                                                  float* __restrict__ c_dst,
                                                  _Float16* __restrict__ h_dst,
                                                  const _Float16* __restrict__ WpT,
                                                  const int* __restrict__ op_idx,
                                                  int op_start, int mshift) {
    const int t = threadIdx.x;
    const int w = t >> 6, l = t & 63, lr = l & 15, lq = l >> 4;
    const int pbase = blockIdx.x * 32;

    int opv[2];
#pragma unroll
    for (int rt = 0; rt < 2; ++rt) {
        int pg = pbase + rt * 16 + lr;
        int ksx = pg >> mshift, j = pg & ((1 << mshift) - 1);
        opv[rt] = op_idx[ksx * 2047 + op_start + j];
    }

    f32x4 acc[2][4];
#pragma unroll
    for (int rt = 0; rt < 2; ++rt)
#pragma unroll
        for (int g = 0; g < 4; ++g) acc[rt][g] = (f32x4)0.f;

#pragma unroll
    for (int kk = 0; kk < 9; ++kk) {
        half8 a[2];
        if (kk < 8) {
            int side = kk >> 2, ko = (kk & 3) * 32 + lq * 8;
#pragma unroll
            for (int rt = 0; rt < 2; ++rt) {
                int row = 2 * (pbase + rt * 16 + lr) + side;
                a[rt] = *(const half8*)(h_src + (size_t)row * 128 + ko);
            }
        } else {
#pragma unroll
            for (int rt = 0; rt < 2; ++rt)
#pragma unroll
                for (int i = 0; i < 8; ++i)
                    a[rt][i] = (_Float16)((lq * 8 + i) == opv[rt] ? 1.f : 0.f);
        }
#pragma unroll
        for (int g = 0; g < 4; ++g) {
            half8 bb = *(const half8*)(WpT + (g * 128 + w * 16 + lr) * 288 + kk * 32 + lq * 8);
#pragma unroll
            for (int rt = 0; rt < 2; ++rt)
                acc[rt][g] = __builtin_amdgcn_mfma_f32_16x16x32_f16(a[rt], bb, acc[rt][g], 0, 0, 0);
        }
    }

    const int d = w * 16 + lr;
#pragma unroll
    for (int rt = 0; rt < 2; ++rt)
#pragma unroll
        for (int j = 0; j < 4; ++j) {
            int p = pbase + rt * 16 + lq * 4 + j;
            float vi = acc[rt][0][j], vl = acc[rt][1][j], vr = acc[rt][2][j], vu = acc[rt][3][j];
            float lc = c_src[(size_t)(2 * p) * 128 + d];
            float rc = c_src[(size_t)(2 * p + 1) * 128 + d];
            float cc = sigm(vi) * tanh_f(vu) + sigm(vl) * lc + sigm(vr) * rc;
            c_dst[(size_t)p * 128 + d] = cc;
            h_dst[(size_t)p * 128 + d] = (_Float16)tanh_f(cc);
        }
}

// ---------------------------------------------------------------------------
// k_deep: levels 6-10 + AND projection. One block per tree, WpT held in regs.
template <bool GSRC>
__device__ __forceinline__ void deep_pass(int np, int opoff,
                                          const _Float16* hS, const _Float16* cS,
                                          const _Float16* __restrict__ gh,
                                          const float* __restrict__ gc, int rowbase,
                                          _Float16* hD, _Float16* cD,
                                          const half8 (&B)[9][4],
                                          const int* s_op, int w, int lq, int lr) {
    f32x4 acc[4];
#pragma unroll
    for (int g = 0; g < 4; ++g) acc[g] = (f32x4)0.f;
    int pidx = lr < np ? lr : np - 1;
    int op = s_op[opoff + pidx];
#pragma unroll
    for (int kk = 0; kk < 9; ++kk) {
        half8 a;
        if (kk < 8) {
            int side = kk >> 2, ko = (kk & 3) * 32 + lq * 8;
            int child = 2 * pidx + side;
            if constexpr (GSRC)
                a = *(const half8*)(gh + (size_t)(rowbase + child) * 128 + ko);
            else
                a = *(const half8*)(hS + child * 128 + (ko ^ ((child & 15) << 3)));
        } else {
#pragma unroll
            for (int i = 0; i < 8; ++i)
                a[i] = (_Float16)((lq * 8 + i) == op ? 1.f : 0.f);
        }
#pragma unroll
        for (int g = 0; g < 4; ++g)
            acc[g] = __builtin_amdgcn_mfma_f32_16x16x32_f16(a, B[kk][g], acc[g], 0, 0, 0);
    }
    const int d = w * 16 + lr;
#pragma unroll
    for (int j = 0; j < 4; ++j) {
        int p = lq * 4 + j;
        if (p < np) {
            float vi = acc[0][j], vl = acc[1][j], vr = acc[2][j], vu = acc[3][j];
            float lc, rc;
            if constexpr (GSRC) {
                lc = gc[(size_t)(rowbase + 2 * p) * 128 + d];
                rc = gc[(size_t)(rowbase + 2 * p + 1) * 128 + d];
            } else {
                lc = (float)cS[(2 * p) * 132 + d];
                rc = (float)cS[(2 * p + 1) * 132 + d];
            }
            float cc = sigm(vi) * tanh_f(vu) + sigm(vl) * lc + sigm(vr) * rc;
            cD[p * 132 + d] = (_Float16)cc;
            hD[p * 128 + (d ^ ((p & 15) << 3))] = (_Float16)tanh_f(cc);
        }
    }
}

__global__ __launch_bounds__(512, 2) void k_deep(const float* __restrict__ g5c,
                                                 const _Float16* __restrict__ g5h,
                                                 const int* __restrict__ op_idx,
                                                 const _Float16* __restrict__ WpT,
                                                 const float* __restrict__ Wa,
                                                 const float* __restrict__ ba,
                                                 float* __restrict__ c2,
                                                 float* __restrict__ h2) {
    __shared__ int s_op[32];
    __shared__ _Float16 hA[16 * 128], cA[16 * 132];
    __shared__ _Float16 hB[8 * 128],  cB[8 * 132];
    const int t = threadIdx.x, w = t >> 6, l = t & 63, lr = l & 15, lq = l >> 4;
    const int tree = blockIdx.x;

    if (t < 31) s_op[t] = op_idx[tree * 2047 + 2016 + t];   // L6:0..15 L7:16..23 L8:24..27 L9:28..29 L10:30
    __syncthreads();

    half8 B[9][4];
#pragma unroll
    for (int kk = 0; kk < 9; ++kk)
#pragma unroll
        for (int g = 0; g < 4; ++g)
            B[kk][g] = *(const half8*)(WpT + (g * 128 + w * 16 + lr) * 288 + kk * 32 + lq * 8);

    deep_pass<true >(16,  0, nullptr, nullptr, g5h, g5c, tree * 32, hA, cA, B, s_op, w, lq, lr);
    __syncthreads();
    deep_pass<false>( 8, 16, hA, cA, nullptr, nullptr, 0, hB, cB, B, s_op, w, lq, lr);
    __syncthreads();
    deep_pass<false>( 4, 24, hB, cB, nullptr, nullptr, 0, hA, cA, B, s_op, w, lq, lr);
    __syncthreads();
    deep_pass<false>( 2, 28, hA, cA, nullptr, nullptr, 0, hB, cB, B, s_op, w, lq, lr);
    __syncthreads();
    deep_pass<false>( 1, 30, hB, cB, nullptr, nullptr, 0, hA, cA, B, s_op, w, lq, lr);
    __syncthreads();

    // AND projection (root = row 0 of A; p=0 swizzle is identity)
    if (t < 256) {
        int dd = t & 127;
        if (t < 128) {
            float a = ba[dd];
            for (int ll = 0; ll < 128; ++ll) a += (float)cA[ll] * Wa[ll * 128 + dd];
            c2[tree * 128 + dd] = a;
        } else {
            float a = ba[128 + dd];
            for (int ll = 0; ll < 128; ++ll) a += (float)hA[ll] * Wa[16384 + ll * 128 + dd];
            h2[tree * 128 + dd] = a;
        }
    }
}

// ---------------------------------------------------------------------------
__global__ __launch_bounds__(128) void k_final(const float* __restrict__ c2,
                                               const float* __restrict__ h2,
                                               const float* __restrict__ init_e,
                                               const float* __restrict__ Wo,
                                               const float* __restrict__ bo,
                                               float* __restrict__ out) {
    __shared__ float s[384];
    const int d = threadIdx.x;
    float cm = c2[d], hm = h2[d];
    for (int k = 1; k < 64; ++k) {
        cm = fminf(cm, c2[k * 128 + d]);
        hm = fminf(hm, h2[k * 128 + d]);
    }
    s[d] = init_e[d];
    s[128 + d] = cm;
    s[256 + d] = hm;
    __syncthreads();
    float a = bo[d];
    for (int l = 0; l < 384; ++l) a += s[l] * Wo[l * 128 + d];
    out[d] = tanhf(a);
}

// ---------------------------------------------------------------------------
extern "C" void kernel_launch(void* const* d_in, const int* in_sizes, int n_in,
                              void* d_out, int out_size, void* d_ws, size_t ws_size,
                              hipStream_t stream) {
    const float* node_emb = (const float*)d_in[0];
    const float* init_emb = (const float*)d_in[1];
    const float* char_emb = (const float*)d_in[2];
    const float* W_child  = (const float*)d_in[3];
    const float* b_child  = (const float*)d_in[4];
    const float* W_x      = (const float*)d_in[5];
    const float* b_x      = (const float*)d_in[6];
    const float* W_leaf   = (const float*)d_in[7];
    const float* b_leaf   = (const float*)d_in[8];
    const float* W_and    = (const float*)d_in[9];
    const float* b_and    = (const float*)d_in[10];
    const float* W_oend   = (const float*)d_in[11];
    const float* b_oend   = (const float*)d_in[12];
    const int* leaf_idx   = (const int*)d_in[13];
    const int* op_idx     = (const int*)d_in[14];
    float* out = (float*)d_out;
    (void)in_sizes; (void)n_in; (void)out_size; (void)ws_size;

    char* p = (char*)d_ws;
    auto carve = [&](size_t bytes) { char* r = p; p += (bytes + 255) & ~255ull; return r; };
    _Float16* WpT   = (_Float16*)carve((size_t)512 * 288 * 2);
    _Float16* WlT   = (_Float16*)carve((size_t)256 * 128 * 2);
    _Float16* c_tab = (_Float16*)carve((size_t)NNODES * 128 * 2);
    _Float16* h_tab = (_Float16*)carve((size_t)NNODES * 128 * 2);
    float*    g2c   = (float*)carve((size_t)16384 * 128 * 4);
    _Float16* g2h   = (_Float16*)carve((size_t)16384 * 128 * 2);
    float*    g3c   = (float*)carve((size_t)8192 * 128 * 4);
    _Float16* g3h   = (_Float16*)carve((size_t)8192 * 128 * 2);
    float*    g4c   = (float*)carve((size_t)4096 * 128 * 4);
    _Float16* g4h   = (_Float16*)carve((size_t)4096 * 128 * 2);
    float*    g5c   = (float*)carve((size_t)2048 * 128 * 4);
    _Float16* g5h   = (_Float16*)carve((size_t)2048 * 128 * 2);
    float*    c2    = (float*)carve(64 * 128 * 4);
    float*    h2    = (float*)carve(64 * 128 * 4);

    k_prep_wpT  <<<512, 256, 0, stream>>>(W_child, WpT);
    k_prep_wlT  <<<128, 256, 0, stream>>>(W_leaf, WlT);
    k_prep_table<<<64, 256, 0, stream>>>(char_emb, W_x, b_x, b_child, WpT);
    k_prep_nodes<<<(NNODES + 31) / 32, 256, 0, stream>>>(node_emb, WlT, b_leaf, c_tab, h_tab);

    k_lo   <<<1024, 256, 0, stream>>>(c_tab, h_tab, leaf_idx, op_idx, WpT, g2c, g2h);
    k_level<<<256, 512, 0, stream>>>(g2c, g2h, g3c, g3h, WpT, op_idx, 1792, 7);  // L3
    k_level<<<128, 512, 0, stream>>>(g3c, g3h, g4c, g4h, WpT, op_idx, 1920, 6);  // L4
    k_level<<< 64, 512, 0, stream>>>(g4c, g4h, g5c, g5h, WpT, op_idx, 1984, 5);  // L5
    k_deep <<< 64, 512, 0, stream>>>(g5c, g5h, op_idx, WpT, W_and, b_and, c2, h2);
    k_final<<<1, 128, 0, stream>>>(c2, h2, init_emb, W_oend, b_oend, out);
}